// Round 8
// baseline (197.033 us; speedup 1.0000x reference)
//
#include <hip/hip_runtime.h>

#define B_ 4
#define C_ 256
#define N_ 4096
#define INTER_ 32

typedef __attribute__((ext_vector_type(8))) short short8;
typedef __attribute__((ext_vector_type(4))) float f32x4;
typedef __attribute__((ext_vector_type(16))) float f32x16;
typedef __attribute__((ext_vector_type(4))) unsigned int u32x4;

#define TILEB 18432              // staged bytes per 32-key tile: V 16KB + K 2KB

static __device__ __forceinline__ unsigned short f2bf(float f) {
    unsigned int u = __builtin_bit_cast(unsigned int, f);
    u += 0x7fff + ((u >> 16) & 1);   // round-to-nearest-even
    return (unsigned short)(u >> 16);
}

static __device__ __forceinline__ unsigned int cvtpk(float lo, float hi) {
    unsigned int r;
    asm("v_cvt_pk_bf16_f32 %0, %1, %2" : "=v"(r) : "v"(lo), "v"(hi));
    return r;
}

static __device__ __forceinline__ void pl32swap(unsigned int& a, unsigned int& b) {
    asm("v_permlane32_swap_b32 %0, %1" : "+v"(a), "+v"(b));
}

static __device__ __forceinline__ void gload16(const void* g, void* l) {
    __builtin_amdgcn_global_load_lds(
        (const __attribute__((address_space(1))) void*)g,
        (__attribute__((address_space(3))) void*)l, 16, 0, 0);
}

// ---------------- W prep: concat + bf16 convert ----------------
__global__ __launch_bounds__(256) void prep_kernel(
    const float* __restrict__ Wq, const float* __restrict__ Wk,
    const float* __restrict__ Wv, unsigned short* __restrict__ wb)
{
    int i = blockIdx.x * 256 + threadIdx.x;      // 0 .. 320*256-1
    int row = i >> 8, col = i & 255;
    float v;
    if (row < 32)      v = Wq[row * 256 + col];
    else if (row < 64) v = Wk[(row - 32) * 256 + col];
    else               v = Wv[(row - 64) * 256 + col];
    wb[i] = f2bf(v);
}

// ---------------- QKV projection as MFMA GEMM ----------------
// q: [b][n][32] bf16, pre-scaled by log2(e)/sqrt(32) (exp2-domain softmax).
// K/V emitted in MFMA-fragment-linear tiles (consumed via linear
// global_load_lds + lane-linear ds_read_b128; see round 6).
__global__ __launch_bounds__(256) void qkv_kernel(
    const float* __restrict__ x, const unsigned short* __restrict__ wb,
    const float* __restrict__ bq, const float* __restrict__ bk,
    const float* __restrict__ bv,
    unsigned short* __restrict__ qb, unsigned short* __restrict__ kfrag,
    unsigned short* __restrict__ vfrag)
{
    const int tid  = threadIdx.x;
    const int wave = tid >> 6;
    const int lane = tid & 63;
    const int l31  = lane & 31;
    const int h2   = lane >> 5;
    const int b    = blockIdx.x >> 6;
    const int n0   = (blockIdx.x & 63) * 64;

    __shared__ unsigned int xsh[64 * 129];   // [n][c/2] u32, row stride 129 dwords

    {
        const float* xb = x + ((size_t)b * C_ + 64 * wave) * N_ + n0 + lane;
        unsigned int* dst = xsh + (size_t)lane * 129 + 32 * wave;
        #pragma unroll 8
        for (int s = 0; s < 32; ++s) {
            float v0 = xb[(size_t)(2 * s) * N_];
            float v1 = xb[(size_t)(2 * s + 1) * N_];
            dst[s] = (unsigned int)f2bf(v0) | ((unsigned int)f2bf(v1) << 16);
        }
    }
    __syncthreads();

    const float rs = 0.25504183f;   // log2(e)/sqrt(32) folded into q

    #pragma unroll
    for (int u = 0; u < 5; ++u) {
        const int unit = wave + 4 * u;       // 0..19
        const int ch = unit >> 1;            // 0..9
        const int ns = unit & 1;
        const int ncol = n0 + 32 * ns + l31;
        const int jt = (n0 >> 5) + ns;

        const float* bias = (ch == 0) ? bq : (ch == 1) ? bk : (bv + (ch - 2) * 32);
        f32x16 acc;
        #pragma unroll
        for (int r = 0; r < 16; ++r)
            acc[r] = bias[(r & 3) + 8 * (r >> 2) + 4 * h2];

        const unsigned short* wrow = wb + ((size_t)(ch * 32 + l31)) * 256 + 8 * h2;
        const unsigned int*   xrow = xsh + (size_t)(32 * ns + l31) * 129 + 4 * h2;

        #pragma unroll
        for (int kk = 0; kk < 16; ++kk) {
            short8 wa = *reinterpret_cast<const short8*>(wrow + 16 * kk);
            short8 xf = *reinterpret_cast<const short8*>(xrow + 8 * kk);
            acc = __builtin_amdgcn_mfma_f32_32x32x16_bf16(wa, xf, acc, 0, 0, 0);
        }

        if (ch == 0) {
            unsigned short* dst = qb + ((size_t)b * N_ + ncol) * 32;
            #pragma unroll
            for (int q = 0; q < 4; ++q) {
                unsigned int w0 = (unsigned int)f2bf(acc[4 * q] * rs)
                                | ((unsigned int)f2bf(acc[4 * q + 1] * rs) << 16);
                unsigned int w1 = (unsigned int)f2bf(acc[4 * q + 2] * rs)
                                | ((unsigned int)f2bf(acc[4 * q + 3] * rs) << 16);
                unsigned int* p = reinterpret_cast<unsigned int*>(dst + 4 * h2 + 8 * q);
                p[0] = w0; p[1] = w1;
            }
        } else if (ch == 1) {
            // K fragment tile: acc[r] = K[kdim=co][j_local=l31]
            unsigned short* kt = kfrag + ((size_t)b * 128 + jt) * 1024;
            #pragma unroll
            for (int r = 0; r < 16; ++r) {
                const int co = (r & 3) + 8 * (r >> 2) + 4 * h2;
                const int addr = ((co >> 4) << 9) + ((l31 + 32 * ((co >> 3) & 1)) << 3)
                               + (co & 7);
                kt[addr] = f2bf(acc[r]);
            }
        } else {
            // V fragment tile: acc[r] = V[c=32g+co][j_local=l31]
            const int g = ch - 2;
            unsigned short* vt_ = vfrag + (((size_t)b * 128 + jt) * 8 + g) * 1024;
            #pragma unroll
            for (int r = 0; r < 16; ++r) {
                const int co = (r & 3) + 8 * (r >> 2) + 4 * h2;
                const int addr = ((l31 >> 4) << 9) + ((co + 32 * ((l31 >> 3) & 1)) << 3)
                               + (l31 & 7);
                vt_[addr] = f2bf(acc[r]);
            }
        }
    }
}

// ---------------- Flash attention: barrier-free wave-private pipeline -------
// grid 256 flat (XCD-batch affinity), block 256 = 4 waves. All 4 waves serve
// the SAME 64 query rows (two 32-row groups A/B sharing every V-fragment
// read -> 2x LDS-read reuse); wave w sweeps j-quarter w. Each wave owns a
// private 2x18KB double buffer staged via global_load_lds and self-synced
// with s_waitcnt vmcnt(0) -- NO __syncthreads in the main loop, so the 4
// waves (1/SIMD) free-run and TA/LDS/VALU/MFMA overlap across them.
// Epilogue: one barrier, 4-way weighted combine through 128KB LDS exchange.
__global__ __launch_bounds__(256, 1) void attn_kernel(
    const unsigned short* __restrict__ qb, const unsigned short* __restrict__ kfrag,
    const unsigned short* __restrict__ vfrag,
    const float* __restrict__ x, const float* __restrict__ gamma,
    float* __restrict__ out)
{
    const int tid  = threadIdx.x;
    const int wave = tid >> 6;     // = j-quarter
    const int lane = tid & 63;
    const int l31  = lane & 31;
    const int h2   = lane >> 5;

    // XCD-affinity decode (bijective): bid = slot*8 + xcd
    const int bid  = blockIdx.x;
    const int xcd  = bid & 7;
    const int slot = bid >> 3;
    const int b    = xcd >> 1;               // 2 XCDs per batch
    const int ib   = slot * 2 + (xcd & 1);   // i-tile 0..63
    const int i0   = ib * 64;

    __shared__ char lds[4 * 2 * TILEB];      // 147456 B: per-wave private dbuf
    __shared__ float m_sh[4][2][32];
    __shared__ float l_sh[4][2][32];

    const unsigned short* vtb = vfrag + (size_t)b * 128 * 8192;
    const unsigned short* ktb = kfrag + (size_t)b * 128 * 1024;

    char* buf0 = lds + wave * (2 * TILEB);
    char* buf1 = buf0 + TILEB;

#define STAGE(jtg_, dst_) do {                                                \
        const char* vs_ = (const char*)(vtb + (size_t)(jtg_) * 8192);         \
        _Pragma("unroll")                                                     \
        for (int s2_ = 0; s2_ < 16; ++s2_)                                    \
            gload16(vs_ + s2_ * 1024 + lane * 16, (dst_) + s2_ * 1024);       \
        const char* ks_ = (const char*)(ktb + (size_t)(jtg_) * 1024);         \
        gload16(ks_ + lane * 16, (dst_) + 16384);                             \
        gload16(ks_ + 1024 + lane * 16, (dst_) + 17408);                      \
    } while (0)

    // Q B-fragments for the two 32-row groups (one-time scattered load)
    const unsigned short* qbase = qb + ((size_t)b * N_ + i0 + l31) * 32 + 8 * h2;
    short8 qa0 = *reinterpret_cast<const short8*>(qbase);
    short8 qa1 = *reinterpret_cast<const short8*>(qbase + 16);
    short8 qb0 = *reinterpret_cast<const short8*>(qbase + 32 * 32);
    short8 qb1 = *reinterpret_cast<const short8*>(qbase + 32 * 32 + 16);

    f32x16 accA[8], accB[8];
    #pragma unroll
    for (int g = 0; g < 8; ++g)
        #pragma unroll
        for (int r = 0; r < 16; ++r) { accA[g][r] = 0.f; accB[g][r] = 0.f; }

    float mA = 0.f, lA = 0.f, mB = 0.f, lB = 0.f;   // defer-max init (exp2 dom.)
    const f32x16 z16 = {};

    // prologue: stage tile 0 of this j-quarter, wait privately
    STAGE(wave * 32, buf0);
    asm volatile("s_waitcnt vmcnt(0)" ::: "memory");
    __builtin_amdgcn_sched_barrier(0);

    #pragma unroll 1
    for (int t = 0; t < 32; ++t) {
        char* cur = (t & 1) ? buf1 : buf0;
        char* nxt = (t & 1) ? buf0 : buf1;

        if (t < 31) STAGE(wave * 32 + t + 1, nxt);   // fire & forget

        // ---- QK^T (swapped): S^T[j][i] for both q-groups ----
        short8 ka0 = *reinterpret_cast<const short8*>(cur + 16384 + lane * 16);
        short8 ka1 = *reinterpret_cast<const short8*>(cur + 17408 + lane * 16);
        f32x16 sA = __builtin_amdgcn_mfma_f32_32x32x16_bf16(ka0, qa0, z16, 0, 0, 0);
        sA = __builtin_amdgcn_mfma_f32_32x32x16_bf16(ka1, qa1, sA, 0, 0, 0);
        f32x16 sB = __builtin_amdgcn_mfma_f32_32x32x16_bf16(ka0, qb0, z16, 0, 0, 0);
        sB = __builtin_amdgcn_mfma_f32_32x32x16_bf16(ka1, qb1, sB, 0, 0, 0);

        short8 pA0, pA1, pB0, pB1;
#define SOFTMAX(s_, m_, l_, acc_, pb0_, pb1_) do {                            \
        float a0 = fmaxf(s_[0], s_[8]),  a1 = fmaxf(s_[1], s_[9]);            \
        float a2 = fmaxf(s_[2], s_[10]), a3 = fmaxf(s_[3], s_[11]);           \
        float a4 = fmaxf(s_[4], s_[12]), a5 = fmaxf(s_[5], s_[13]);           \
        float a6 = fmaxf(s_[6], s_[14]), a7 = fmaxf(s_[7], s_[15]);           \
        a0 = fmaxf(a0, a4); a1 = fmaxf(a1, a5);                               \
        a2 = fmaxf(a2, a6); a3 = fmaxf(a3, a7);                               \
        float smax = fmaxf(fmaxf(a0, a1), fmaxf(a2, a3));                     \
        if (__any(smax > m_ + 8.0f)) {                                        \
            float sm2 = fmaxf(smax, __shfl_xor(smax, 32));                    \
            float mnew = fmaxf(m_, sm2);                                      \
            float corr = exp2f(m_ - mnew);                                    \
            m_ = mnew; l_ *= corr;                                            \
            _Pragma("unroll")                                                 \
            for (int g_ = 0; g_ < 8; ++g_)                                    \
                _Pragma("unroll")                                             \
                for (int r_ = 0; r_ < 16; ++r_) acc_[g_][r_] *= corr;         \
        }                                                                     \
        float p_[16]; float lsum_ = 0.f;                                      \
        _Pragma("unroll")                                                     \
        for (int r_ = 0; r_ < 16; ++r_) {                                     \
            p_[r_] = exp2f(s_[r_] - m_); lsum_ += p_[r_];                     \
        }                                                                     \
        l_ += lsum_;                                                          \
        unsigned int X0 = cvtpk(p_[0],  p_[1]),  X1 = cvtpk(p_[2],  p_[3]);   \
        unsigned int Y0 = cvtpk(p_[4],  p_[5]),  Y1 = cvtpk(p_[6],  p_[7]);   \
        unsigned int W0 = cvtpk(p_[8],  p_[9]),  W1 = cvtpk(p_[10], p_[11]);  \
        unsigned int V0 = cvtpk(p_[12], p_[13]), V1 = cvtpk(p_[14], p_[15]);  \
        pl32swap(X0, Y0); pl32swap(X1, Y1);                                   \
        pl32swap(W0, V0); pl32swap(W1, V1);                                   \
        pb0_ = __builtin_bit_cast(short8, u32x4{X0, X1, Y0, Y1});             \
        pb1_ = __builtin_bit_cast(short8, u32x4{W0, W1, V0, V1});             \
    } while (0)

        SOFTMAX(sA, mA, lA, accA, pA0, pA1);
        SOFTMAX(sB, mB, lB, accB, pB0, pB1);

        // ---- PV: each V fragment read once, used by BOTH q-groups ----
        __builtin_amdgcn_s_setprio(1);
        #pragma unroll
        for (int g = 0; g < 4; ++g) {
            short8 va0 = *reinterpret_cast<const short8*>(cur + g * 2048 + lane * 16);
            short8 va1 = *reinterpret_cast<const short8*>(cur + g * 2048 + 1024 + lane * 16);
            accA[g] = __builtin_amdgcn_mfma_f32_32x32x16_bf16(va0, pA0, accA[g], 0, 0, 0);
            accA[g] = __builtin_amdgcn_mfma_f32_32x32x16_bf16(va1, pA1, accA[g], 0, 0, 0);
            accB[g] = __builtin_amdgcn_mfma_f32_32x32x16_bf16(va0, pB0, accB[g], 0, 0, 0);
            accB[g] = __builtin_amdgcn_mfma_f32_32x32x16_bf16(va1, pB1, accB[g], 0, 0, 0);
        }
        __builtin_amdgcn_sched_barrier(0);   // cap live-range of va regs
        #pragma unroll
        for (int g = 4; g < 8; ++g) {
            short8 va0 = *reinterpret_cast<const short8*>(cur + g * 2048 + lane * 16);
            short8 va1 = *reinterpret_cast<const short8*>(cur + g * 2048 + 1024 + lane * 16);
            accA[g] = __builtin_amdgcn_mfma_f32_32x32x16_bf16(va0, pA0, accA[g], 0, 0, 0);
            accA[g] = __builtin_amdgcn_mfma_f32_32x32x16_bf16(va1, pA1, accA[g], 0, 0, 0);
            accB[g] = __builtin_amdgcn_mfma_f32_32x32x16_bf16(va0, pB0, accB[g], 0, 0, 0);
            accB[g] = __builtin_amdgcn_mfma_f32_32x32x16_bf16(va1, pB1, accB[g], 0, 0, 0);
        }
        __builtin_amdgcn_s_setprio(0);

        // private double-buffer sync: next tile must have landed
        asm volatile("s_waitcnt vmcnt(0)" ::: "memory");
        __builtin_amdgcn_sched_barrier(0);
    }
#undef STAGE
#undef SOFTMAX

    // ---- 4-way j-combine ----
    float ltA = lA + __shfl_xor(lA, 32);
    float ltB = lB + __shfl_xor(lB, 32);
    if (lane < 32) {
        m_sh[wave][0][lane] = mA; l_sh[wave][0][lane] = ltA;
        m_sh[wave][1][lane] = mB; l_sh[wave][1][lane] = ltB;
    }
    __syncthreads();

    float MA = -1e30f, MB = -1e30f, LA = 0.f, LB = 0.f;
    #pragma unroll
    for (int w = 0; w < 4; ++w) {
        MA = fmaxf(MA, m_sh[w][0][l31]);
        MB = fmaxf(MB, m_sh[w][1][l31]);
    }
    #pragma unroll
    for (int w = 0; w < 4; ++w) {
        LA += exp2f(m_sh[w][0][l31] - MA) * l_sh[w][0][l31];
        LB += exp2f(m_sh[w][1][l31] - MB) * l_sh[w][1][l31];
    }
    const float wgtA = exp2f(mA - MA);
    const float wgtB = exp2f(mB - MB);
    #pragma unroll
    for (int g = 0; g < 8; ++g)
        #pragma unroll
        for (int r = 0; r < 16; ++r) { accA[g][r] *= wgtA; accB[g][r] *= wgtB; }

    const float gma  = gamma[0];
    const float invLA = 1.f / LA;
    const float invLB = 1.f / LB;
    f32x4* D = reinterpret_cast<f32x4*>(lds);   // 128KB exchange region

    // ---- phase A: dump all waves' accA, each wave sums+stores 2 g-slices ----
    #pragma unroll
    for (int g = 0; g < 8; ++g)
        #pragma unroll
        for (int r4 = 0; r4 < 4; ++r4) {
            f32x4 tv;
            #pragma unroll
            for (int e = 0; e < 4; ++e) tv[e] = accA[g][4 * r4 + e];
            D[((wave * 8 + g) * 4 + r4) * 64 + lane] = tv;
        }
    __syncthreads();
    #pragma unroll
    for (int gi = 0; gi < 2; ++gi) {
        const int g = wave * 2 + gi;
        #pragma unroll
        for (int r4 = 0; r4 < 4; ++r4) {
            f32x4 s0 = D[((0 * 8 + g) * 4 + r4) * 64 + lane];
            f32x4 s1 = D[((1 * 8 + g) * 4 + r4) * 64 + lane];
            f32x4 s2 = D[((2 * 8 + g) * 4 + r4) * 64 + lane];
            f32x4 s3 = D[((3 * 8 + g) * 4 + r4) * 64 + lane];
            #pragma unroll
            for (int e = 0; e < 4; ++e) {
                const float v = s0[e] + s1[e] + s2[e] + s3[e];
                const int c = 32 * g + e + 8 * r4 + 4 * h2;
                const size_t off = ((size_t)b * C_ + c) * N_ + i0 + l31;
                out[off] = gma * v * invLA + x[off];
            }
        }
    }
    __syncthreads();

    // ---- phase B ----
    #pragma unroll
    for (int g = 0; g < 8; ++g)
        #pragma unroll
        for (int r4 = 0; r4 < 4; ++r4) {
            f32x4 tv;
            #pragma unroll
            for (int e = 0; e < 4; ++e) tv[e] = accB[g][4 * r4 + e];
            D[((wave * 8 + g) * 4 + r4) * 64 + lane] = tv;
        }
    __syncthreads();
    #pragma unroll
    for (int gi = 0; gi < 2; ++gi) {
        const int g = wave * 2 + gi;
        #pragma unroll
        for (int r4 = 0; r4 < 4; ++r4) {
            f32x4 s0 = D[((0 * 8 + g) * 4 + r4) * 64 + lane];
            f32x4 s1 = D[((1 * 8 + g) * 4 + r4) * 64 + lane];
            f32x4 s2 = D[((2 * 8 + g) * 4 + r4) * 64 + lane];
            f32x4 s3 = D[((3 * 8 + g) * 4 + r4) * 64 + lane];
            #pragma unroll
            for (int e = 0; e < 4; ++e) {
                const float v = s0[e] + s1[e] + s2[e] + s3[e];
                const int c = 32 * g + e + 8 * r4 + 4 * h2;
                const size_t off = ((size_t)b * C_ + c) * N_ + i0 + 32 + l31;
                out[off] = gma * v * invLB + x[off];
            }
        }
    }
}

extern "C" void kernel_launch(void* const* d_in, const int* in_sizes, int n_in,
                              void* d_out, int out_size, void* d_ws, size_t ws_size,
                              hipStream_t stream) {
    const float* x     = (const float*)d_in[0];
    const float* Wq    = (const float*)d_in[1];
    const float* bq    = (const float*)d_in[2];
    const float* Wk    = (const float*)d_in[3];
    const float* bk    = (const float*)d_in[4];
    const float* Wv    = (const float*)d_in[5];
    const float* bv    = (const float*)d_in[6];
    const float* gamma = (const float*)d_in[7];
    float* out = (float*)d_out;

    unsigned short* ws = (unsigned short*)d_ws;
    unsigned short* qb    = ws;                                 // B*N*32 bf16
    unsigned short* kfrag = qb + (size_t)B_ * N_ * INTER_;      // B*128*1024 bf16
    unsigned short* vfrag = kfrag + (size_t)B_ * 128 * 1024;    // B*128*8192 bf16
    unsigned short* wb    = vfrag + (size_t)B_ * 128 * 8192;    // 320*256 bf16

    prep_kernel<<<dim3(320), 256, 0, stream>>>(Wq, Wk, Wv, wb);
    qkv_kernel<<<dim3(B_ * (N_ / 64)), 256, 0, stream>>>(
        x, wb, bq, bk, bv, qb, kfrag, vfrag);
    attn_kernel<<<dim3(256), 256, 0, stream>>>(
        qb, kfrag, vfrag, x, gamma, out);
}

// Round 9
// 97.718 us; speedup vs baseline: 2.0163x; 2.0163x over previous
//
#include <hip/hip_runtime.h>

#define B_ 4
#define C_ 256
#define N_ 4096
#define INTER_ 32

typedef __attribute__((ext_vector_type(8))) short short8;
typedef __attribute__((ext_vector_type(4))) float f32x4;
typedef __attribute__((ext_vector_type(16))) float f32x16;
typedef __attribute__((ext_vector_type(4))) unsigned int u32x4;

#define TILEB 18432              // staged bytes per 32-key tile: V 16KB + K 2KB

static __device__ __forceinline__ unsigned short f2bf(float f) {
    unsigned int u = __builtin_bit_cast(unsigned int, f);
    u += 0x7fff + ((u >> 16) & 1);   // round-to-nearest-even
    return (unsigned short)(u >> 16);
}

static __device__ __forceinline__ unsigned int cvtpk(float lo, float hi) {
    unsigned int r;
    asm("v_cvt_pk_bf16_f32 %0, %1, %2" : "=v"(r) : "v"(lo), "v"(hi));
    return r;
}

static __device__ __forceinline__ void pl32swap(unsigned int& a, unsigned int& b) {
    asm("v_permlane32_swap_b32 %0, %1" : "+v"(a), "+v"(b));
}

static __device__ __forceinline__ void gload16(const void* g, void* l) {
    __builtin_amdgcn_global_load_lds(
        (const __attribute__((address_space(1))) void*)g,
        (__attribute__((address_space(3))) void*)l, 16, 0, 0);
}

// ---------------- W prep: concat + bf16 convert ----------------
__global__ __launch_bounds__(256) void prep_kernel(
    const float* __restrict__ Wq, const float* __restrict__ Wk,
    const float* __restrict__ Wv, unsigned short* __restrict__ wb)
{
    int i = blockIdx.x * 256 + threadIdx.x;      // 0 .. 320*256-1
    int row = i >> 8, col = i & 255;
    float v;
    if (row < 32)      v = Wq[row * 256 + col];
    else if (row < 64) v = Wk[(row - 32) * 256 + col];
    else               v = Wv[(row - 64) * 256 + col];
    wb[i] = f2bf(v);
}

// ---------------- QKV projection as MFMA GEMM ----------------
// q: [b][n][32] bf16, pre-scaled by log2(e)/sqrt(32) (exp2-domain softmax).
// K/V emitted in MFMA-fragment-linear tiles (consumed via linear
// global_load_lds + lane-linear ds_read_b128; see round 6).
__global__ __launch_bounds__(256) void qkv_kernel(
    const float* __restrict__ x, const unsigned short* __restrict__ wb,
    const float* __restrict__ bq, const float* __restrict__ bk,
    const float* __restrict__ bv,
    unsigned short* __restrict__ qb, unsigned short* __restrict__ kfrag,
    unsigned short* __restrict__ vfrag)
{
    const int tid  = threadIdx.x;
    const int wave = tid >> 6;
    const int lane = tid & 63;
    const int l31  = lane & 31;
    const int h2   = lane >> 5;
    const int b    = blockIdx.x >> 6;
    const int n0   = (blockIdx.x & 63) * 64;

    __shared__ unsigned int xsh[64 * 129];   // [n][c/2] u32, row stride 129 dwords

    {
        const float* xb = x + ((size_t)b * C_ + 64 * wave) * N_ + n0 + lane;
        unsigned int* dst = xsh + (size_t)lane * 129 + 32 * wave;
        #pragma unroll 8
        for (int s = 0; s < 32; ++s) {
            float v0 = xb[(size_t)(2 * s) * N_];
            float v1 = xb[(size_t)(2 * s + 1) * N_];
            dst[s] = (unsigned int)f2bf(v0) | ((unsigned int)f2bf(v1) << 16);
        }
    }
    __syncthreads();

    const float rs = 0.25504183f;   // log2(e)/sqrt(32) folded into q

    #pragma unroll
    for (int u = 0; u < 5; ++u) {
        const int unit = wave + 4 * u;       // 0..19
        const int ch = unit >> 1;            // 0..9
        const int ns = unit & 1;
        const int ncol = n0 + 32 * ns + l31;
        const int jt = (n0 >> 5) + ns;

        const float* bias = (ch == 0) ? bq : (ch == 1) ? bk : (bv + (ch - 2) * 32);
        f32x16 acc;
        #pragma unroll
        for (int r = 0; r < 16; ++r)
            acc[r] = bias[(r & 3) + 8 * (r >> 2) + 4 * h2];

        const unsigned short* wrow = wb + ((size_t)(ch * 32 + l31)) * 256 + 8 * h2;
        const unsigned int*   xrow = xsh + (size_t)(32 * ns + l31) * 129 + 4 * h2;

        #pragma unroll
        for (int kk = 0; kk < 16; ++kk) {
            short8 wa = *reinterpret_cast<const short8*>(wrow + 16 * kk);
            short8 xf = *reinterpret_cast<const short8*>(xrow + 8 * kk);
            acc = __builtin_amdgcn_mfma_f32_32x32x16_bf16(wa, xf, acc, 0, 0, 0);
        }

        if (ch == 0) {
            unsigned short* dst = qb + ((size_t)b * N_ + ncol) * 32;
            #pragma unroll
            for (int q = 0; q < 4; ++q) {
                unsigned int w0 = (unsigned int)f2bf(acc[4 * q] * rs)
                                | ((unsigned int)f2bf(acc[4 * q + 1] * rs) << 16);
                unsigned int w1 = (unsigned int)f2bf(acc[4 * q + 2] * rs)
                                | ((unsigned int)f2bf(acc[4 * q + 3] * rs) << 16);
                unsigned int* p = reinterpret_cast<unsigned int*>(dst + 4 * h2 + 8 * q);
                p[0] = w0; p[1] = w1;
            }
        } else if (ch == 1) {
            // K fragment tile: acc[r] = K[kdim=co][j_local=l31]
            unsigned short* kt = kfrag + ((size_t)b * 128 + jt) * 1024;
            #pragma unroll
            for (int r = 0; r < 16; ++r) {
                const int co = (r & 3) + 8 * (r >> 2) + 4 * h2;
                const int addr = ((co >> 4) << 9) + ((l31 + 32 * ((co >> 3) & 1)) << 3)
                               + (co & 7);
                kt[addr] = f2bf(acc[r]);
            }
        } else {
            // V fragment tile: acc[r] = V[c=32g+co][j_local=l31]
            const int g = ch - 2;
            unsigned short* vt_ = vfrag + (((size_t)b * 128 + jt) * 8 + g) * 1024;
            #pragma unroll
            for (int r = 0; r < 16; ++r) {
                const int co = (r & 3) + 8 * (r >> 2) + 4 * h2;
                const int addr = ((l31 >> 4) << 9) + ((co + 32 * ((l31 >> 3) & 1)) << 3)
                               + (l31 & 7);
                vt_[addr] = f2bf(acc[r]);
            }
        }
    }
}

// ---------------- Flash attention: barrier-free wave-private pipeline -------
// grid 512 flat (XCD-batch affinity), block 256 = 4 waves. All 4 waves serve
// the SAME 32 query rows; wave w sweeps j-quarter w with a PRIVATE single
// 18KB buffer: per step, hoist all 18 ds_read_b128 to regs, lgkm-fence,
// fire 18 global_load_lds for the next tile into the same buffer, compute
// (QK^T, exp2 softmax, PV) from regs, then vmcnt(0). No __syncthreads in the
// main loop. LDS 74KB -> 2 independent blocks/CU cross-cover stalls.
// acc = 8 x f32x16 = 128 VGPR (hard budget; r5/r8 spilled above this).
__global__ __launch_bounds__(256, 2) void attn_kernel(
    const unsigned short* __restrict__ qb, const unsigned short* __restrict__ kfrag,
    const unsigned short* __restrict__ vfrag,
    const float* __restrict__ x, const float* __restrict__ gamma,
    float* __restrict__ out)
{
    const int tid  = threadIdx.x;
    const int wave = tid >> 6;     // = j-quarter
    const int lane = tid & 63;
    const int l31  = lane & 31;
    const int h2   = lane >> 5;

    // XCD-affinity decode (bijective over 512): bid = slot*8 + xcd
    const int bid  = blockIdx.x;
    const int xcd  = bid & 7;
    const int slot = bid >> 3;               // 0..63
    const int b    = xcd >> 1;               // 2 XCDs per batch
    const int ib   = (xcd & 1) * 64 + slot;  // i-tile 0..127
    const int i0   = ib * 32;

    __shared__ char lds[4 * TILEB];          // 73728 B: per-wave private buffer
    __shared__ float m_sh[4][32];
    __shared__ float l_sh[4][32];

    const unsigned short* vtb = vfrag + (size_t)b * 128 * 8192;
    const unsigned short* ktb = kfrag + (size_t)b * 128 * 1024;

    char* buf = lds + wave * TILEB;

#define STAGE(jtg_) do {                                                      \
        const char* vs_ = (const char*)(vtb + (size_t)(jtg_) * 8192);         \
        _Pragma("unroll")                                                     \
        for (int s2_ = 0; s2_ < 16; ++s2_)                                    \
            gload16(vs_ + s2_ * 1024 + lane * 16, buf + s2_ * 1024);          \
        const char* ks_ = (const char*)(ktb + (size_t)(jtg_) * 1024);         \
        gload16(ks_ + lane * 16, buf + 16384);                                \
        gload16(ks_ + 1024 + lane * 16, buf + 17408);                         \
    } while (0)

    // Q B-fragments (one-time scattered load)
    const unsigned short* qbase = qb + ((size_t)b * N_ + i0 + l31) * 32 + 8 * h2;
    short8 qf0 = *reinterpret_cast<const short8*>(qbase);
    short8 qf1 = *reinterpret_cast<const short8*>(qbase + 16);

    f32x16 acc[8];
    #pragma unroll
    for (int g = 0; g < 8; ++g)
        #pragma unroll
        for (int r = 0; r < 16; ++r) acc[g][r] = 0.f;

    float m_run = 0.f, l_run = 0.f;          // defer-max init (exp2 domain)
    const f32x16 z16 = {};

    // prologue: stage tile 0 of this j-quarter, wait privately
    STAGE(wave * 32);
    asm volatile("s_waitcnt vmcnt(0)" ::: "memory");
    __builtin_amdgcn_sched_barrier(0);

    #pragma unroll 1
    for (int t = 0; t < 32; ++t) {
        // ---- hoist the whole tile to regs (18 x ds_read_b128) ----
        short8 ka0 = *reinterpret_cast<const short8*>(buf + 16384 + lane * 16);
        short8 ka1 = *reinterpret_cast<const short8*>(buf + 17408 + lane * 16);
        short8 va[16];
        #pragma unroll
        for (int g = 0; g < 8; ++g) {
            va[2 * g]     = *reinterpret_cast<const short8*>(buf + g * 2048 + lane * 16);
            va[2 * g + 1] = *reinterpret_cast<const short8*>(buf + g * 2048 + 1024 + lane * 16);
        }
        asm volatile("s_waitcnt lgkmcnt(0)" ::: "memory");   // reads done, buf free
        __builtin_amdgcn_sched_barrier(0);

        // ---- fire next tile into the SAME buffer (fire & forget) ----
        if (t < 31) STAGE(wave * 32 + t + 1);

        // ---- QK^T (swapped): S^T[j][i], scores in log2 units ----
        f32x16 s = __builtin_amdgcn_mfma_f32_32x32x16_bf16(ka0, qf0, z16, 0, 0, 0);
        s = __builtin_amdgcn_mfma_f32_32x32x16_bf16(ka1, qf1, s, 0, 0, 0);

        // ---- online softmax (exp2 domain), lane-local (i = l31) ----
        float a0 = fmaxf(s[0], s[8]),  a1 = fmaxf(s[1], s[9]);
        float a2 = fmaxf(s[2], s[10]), a3 = fmaxf(s[3], s[11]);
        float a4 = fmaxf(s[4], s[12]), a5 = fmaxf(s[5], s[13]);
        float a6 = fmaxf(s[6], s[14]), a7 = fmaxf(s[7], s[15]);
        a0 = fmaxf(a0, a4); a1 = fmaxf(a1, a5); a2 = fmaxf(a2, a6); a3 = fmaxf(a3, a7);
        float smax = fmaxf(fmaxf(a0, a1), fmaxf(a2, a3));

        if (__any(smax > m_run + 8.0f)) {    // defer-max: rare slow path
            float sm2 = fmaxf(smax, __shfl_xor(smax, 32));
            float mnew = fmaxf(m_run, sm2);
            float corr = exp2f(m_run - mnew);
            m_run = mnew;
            l_run *= corr;
            #pragma unroll
            for (int g = 0; g < 8; ++g)
                #pragma unroll
                for (int r = 0; r < 16; ++r) acc[g][r] *= corr;
        }

        float p[16];
        float lsum = 0.f;
        #pragma unroll
        for (int r = 0; r < 16; ++r) { p[r] = exp2f(s[r] - m_run); lsum += p[r]; }
        l_run += lsum;

        unsigned int X0 = cvtpk(p[0],  p[1]),  X1 = cvtpk(p[2],  p[3]);
        unsigned int Y0 = cvtpk(p[4],  p[5]),  Y1 = cvtpk(p[6],  p[7]);
        unsigned int W0 = cvtpk(p[8],  p[9]),  W1 = cvtpk(p[10], p[11]);
        unsigned int V0 = cvtpk(p[12], p[13]), V1 = cvtpk(p[14], p[15]);
        pl32swap(X0, Y0); pl32swap(X1, Y1);
        pl32swap(W0, V0); pl32swap(W1, V1);
        short8 pb0 = __builtin_bit_cast(short8, u32x4{X0, X1, Y0, Y1});
        short8 pb1 = __builtin_bit_cast(short8, u32x4{W0, W1, V0, V1});

        // ---- PV from regs ----
        __builtin_amdgcn_s_setprio(1);
        #pragma unroll
        for (int g = 0; g < 8; ++g) {
            acc[g] = __builtin_amdgcn_mfma_f32_32x32x16_bf16(va[2 * g],     pb0, acc[g], 0, 0, 0);
            acc[g] = __builtin_amdgcn_mfma_f32_32x32x16_bf16(va[2 * g + 1], pb1, acc[g], 0, 0, 0);
        }
        __builtin_amdgcn_s_setprio(0);

        // private sync: next tile must have landed before next step's reads
        asm volatile("s_waitcnt vmcnt(0)" ::: "memory");
        __builtin_amdgcn_sched_barrier(0);
    }
#undef STAGE

    // ---- 4-way j-combine ----
    float l_tot = l_run + __shfl_xor(l_run, 32);
    if (lane < 32) { m_sh[wave][lane] = m_run; l_sh[wave][lane] = l_tot; }
    __syncthreads();

    float M = -1e30f, L = 0.f;
    #pragma unroll
    for (int w = 0; w < 4; ++w) M = fmaxf(M, m_sh[w][l31]);
    #pragma unroll
    for (int w = 0; w < 4; ++w) L += exp2f(m_sh[w][l31] - M) * l_sh[w][l31];
    const float wgt = exp2f(m_run - M);
    #pragma unroll
    for (int g = 0; g < 8; ++g)
        #pragma unroll
        for (int r = 0; r < 16; ++r) acc[g][r] *= wgt;

    const float gma  = gamma[0];
    const float invL = 1.f / L;
    f32x4* D = reinterpret_cast<f32x4*>(lds);    // 64KB exchange (fits in 72KB)

    // two phases of 4 g-groups each: dump all waves, wave w reduces g = base+w
    #pragma unroll
    for (int ph = 0; ph < 2; ++ph) {
        const int gbase = ph * 4;
        __syncthreads();
        #pragma unroll
        for (int gl = 0; gl < 4; ++gl) {
            const int g = gbase + gl;
            #pragma unroll
            for (int r4 = 0; r4 < 4; ++r4) {
                f32x4 tv;
                #pragma unroll
                for (int e = 0; e < 4; ++e) tv[e] = acc[g][4 * r4 + e];
                D[((wave * 4 + gl) * 4 + r4) * 64 + lane] = tv;
            }
        }
        __syncthreads();
        const int g = gbase + wave;              // this wave reduces one g
        #pragma unroll
        for (int r4 = 0; r4 < 4; ++r4) {
            f32x4 s0 = D[((0 * 4 + wave) * 4 + r4) * 64 + lane];
            f32x4 s1 = D[((1 * 4 + wave) * 4 + r4) * 64 + lane];
            f32x4 s2 = D[((2 * 4 + wave) * 4 + r4) * 64 + lane];
            f32x4 s3 = D[((3 * 4 + wave) * 4 + r4) * 64 + lane];
            #pragma unroll
            for (int e = 0; e < 4; ++e) {
                const float v = s0[e] + s1[e] + s2[e] + s3[e];
                const int c = 32 * g + e + 8 * r4 + 4 * h2;
                const size_t off = ((size_t)b * C_ + c) * N_ + i0 + l31;
                out[off] = gma * v * invL + x[off];
            }
        }
    }
}

extern "C" void kernel_launch(void* const* d_in, const int* in_sizes, int n_in,
                              void* d_out, int out_size, void* d_ws, size_t ws_size,
                              hipStream_t stream) {
    const float* x     = (const float*)d_in[0];
    const float* Wq    = (const float*)d_in[1];
    const float* bq    = (const float*)d_in[2];
    const float* Wk    = (const float*)d_in[3];
    const float* bk    = (const float*)d_in[4];
    const float* Wv    = (const float*)d_in[5];
    const float* bv    = (const float*)d_in[6];
    const float* gamma = (const float*)d_in[7];
    float* out = (float*)d_out;

    unsigned short* ws = (unsigned short*)d_ws;
    unsigned short* qb    = ws;                                 // B*N*32 bf16
    unsigned short* kfrag = qb + (size_t)B_ * N_ * INTER_;      // B*128*1024 bf16
    unsigned short* vfrag = kfrag + (size_t)B_ * 128 * 1024;    // B*128*8192 bf16
    unsigned short* wb    = vfrag + (size_t)B_ * 128 * 8192;    // 320*256 bf16

    prep_kernel<<<dim3(320), 256, 0, stream>>>(Wq, Wk, Wv, wb);
    qkv_kernel<<<dim3(B_ * (N_ / 64)), 256, 0, stream>>>(
        x, wb, bq, bk, bv, qb, kfrag, vfrag);
    attn_kernel<<<dim3(512), 256, 0, stream>>>(
        qb, kfrag, vfrag, x, gamma, out);
}

// Round 10
// 82.222 us; speedup vs baseline: 2.3964x; 1.1885x over previous
//
#include <hip/hip_runtime.h>

#define B_ 4
#define C_ 256
#define N_ 4096
#define INTER_ 32

typedef __attribute__((ext_vector_type(8))) short short8;
typedef __attribute__((ext_vector_type(4))) float f32x4;
typedef __attribute__((ext_vector_type(16))) float f32x16;
typedef __attribute__((ext_vector_type(4))) unsigned int u32x4;

#define TILEB 18432              // staged bytes per j-tile: V 16KB + K 2KB
#define NSTG  (8 * TILEB)        // 4 jq * 2 buf = 147456 B

static __device__ __forceinline__ unsigned short f2bf(float f) {
    unsigned int u = __builtin_bit_cast(unsigned int, f);
    u += 0x7fff + ((u >> 16) & 1);   // round-to-nearest-even
    return (unsigned short)(u >> 16);
}

static __device__ __forceinline__ unsigned int cvtpk(float lo, float hi) {
    unsigned int r;
    asm("v_cvt_pk_bf16_f32 %0, %1, %2" : "=v"(r) : "v"(lo), "v"(hi));
    return r;
}

static __device__ __forceinline__ void pl32swap(unsigned int& a, unsigned int& b) {
    asm("v_permlane32_swap_b32 %0, %1" : "+v"(a), "+v"(b));
}

static __device__ __forceinline__ float exp2a(float x) {   // bare v_exp_f32: 2^x
    float r;
    asm("v_exp_f32 %0, %1" : "=v"(r) : "v"(x));
    return r;
}

static __device__ __forceinline__ void gload16(const void* g, void* l) {
    __builtin_amdgcn_global_load_lds(
        (const __attribute__((address_space(1))) void*)g,
        (__attribute__((address_space(3))) void*)l, 16, 0, 0);
}

// ---------------- W prep: concat + bf16 convert ----------------
__global__ __launch_bounds__(256) void prep_kernel(
    const float* __restrict__ Wq, const float* __restrict__ Wk,
    const float* __restrict__ Wv, unsigned short* __restrict__ wb)
{
    int i = blockIdx.x * 256 + threadIdx.x;      // 0 .. 320*256-1
    int row = i >> 8, col = i & 255;
    float v;
    if (row < 32)      v = Wq[row * 256 + col];
    else if (row < 64) v = Wk[(row - 32) * 256 + col];
    else               v = Wv[(row - 64) * 256 + col];
    wb[i] = f2bf(v);
}

// ---------------- QKV projection as MFMA GEMM ----------------
// q: [b][n][32] bf16, pre-scaled by log2(e)/sqrt(32) (exp2-domain softmax).
// K/V emitted in MFMA-fragment-linear tiles (consumed via linear
// global_load_lds + lane-linear ds_read_b128; see round 6).
__global__ __launch_bounds__(256) void qkv_kernel(
    const float* __restrict__ x, const unsigned short* __restrict__ wb,
    const float* __restrict__ bq, const float* __restrict__ bk,
    const float* __restrict__ bv,
    unsigned short* __restrict__ qb, unsigned short* __restrict__ kfrag,
    unsigned short* __restrict__ vfrag)
{
    const int tid  = threadIdx.x;
    const int wave = tid >> 6;
    const int lane = tid & 63;
    const int l31  = lane & 31;
    const int h2   = lane >> 5;
    const int b    = blockIdx.x >> 6;
    const int n0   = (blockIdx.x & 63) * 64;

    __shared__ unsigned int xsh[64 * 129];   // [n][c/2] u32, row stride 129 dwords

    {
        const float* xb = x + ((size_t)b * C_ + 64 * wave) * N_ + n0 + lane;
        unsigned int* dst = xsh + (size_t)lane * 129 + 32 * wave;
        #pragma unroll 8
        for (int s = 0; s < 32; ++s) {
            float v0 = xb[(size_t)(2 * s) * N_];
            float v1 = xb[(size_t)(2 * s + 1) * N_];
            dst[s] = (unsigned int)f2bf(v0) | ((unsigned int)f2bf(v1) << 16);
        }
    }
    __syncthreads();

    const float rs = 0.25504183f;   // log2(e)/sqrt(32) folded into q

    #pragma unroll
    for (int u = 0; u < 5; ++u) {
        const int unit = wave + 4 * u;       // 0..19
        const int ch = unit >> 1;            // 0..9
        const int ns = unit & 1;
        const int ncol = n0 + 32 * ns + l31;
        const int jt = (n0 >> 5) + ns;

        const float* bias = (ch == 0) ? bq : (ch == 1) ? bk : (bv + (ch - 2) * 32);
        f32x16 acc;
        #pragma unroll
        for (int r = 0; r < 16; ++r)
            acc[r] = bias[(r & 3) + 8 * (r >> 2) + 4 * h2];

        const unsigned short* wrow = wb + ((size_t)(ch * 32 + l31)) * 256 + 8 * h2;
        const unsigned int*   xrow = xsh + (size_t)(32 * ns + l31) * 129 + 4 * h2;

        #pragma unroll
        for (int kk = 0; kk < 16; ++kk) {
            short8 wa = *reinterpret_cast<const short8*>(wrow + 16 * kk);
            short8 xf = *reinterpret_cast<const short8*>(xrow + 8 * kk);
            acc = __builtin_amdgcn_mfma_f32_32x32x16_bf16(wa, xf, acc, 0, 0, 0);
        }

        if (ch == 0) {
            unsigned short* dst = qb + ((size_t)b * N_ + ncol) * 32;
            #pragma unroll
            for (int q = 0; q < 4; ++q) {
                unsigned int w0 = (unsigned int)f2bf(acc[4 * q] * rs)
                                | ((unsigned int)f2bf(acc[4 * q + 1] * rs) << 16);
                unsigned int w1 = (unsigned int)f2bf(acc[4 * q + 2] * rs)
                                | ((unsigned int)f2bf(acc[4 * q + 3] * rs) << 16);
                unsigned int* p = reinterpret_cast<unsigned int*>(dst + 4 * h2 + 8 * q);
                p[0] = w0; p[1] = w1;
            }
        } else if (ch == 1) {
            // K fragment tile: acc[r] = K[kdim=co][j_local=l31]
            unsigned short* kt = kfrag + ((size_t)b * 128 + jt) * 1024;
            #pragma unroll
            for (int r = 0; r < 16; ++r) {
                const int co = (r & 3) + 8 * (r >> 2) + 4 * h2;
                const int addr = ((co >> 4) << 9) + ((l31 + 32 * ((co >> 3) & 1)) << 3)
                               + (co & 7);
                kt[addr] = f2bf(acc[r]);
            }
        } else {
            // V fragment tile: acc[r] = V[c=32g+co][j_local=l31]
            const int g = ch - 2;
            unsigned short* vt_ = vfrag + (((size_t)b * 128 + jt) * 8 + g) * 1024;
            #pragma unroll
            for (int r = 0; r < 16; ++r) {
                const int co = (r & 3) + 8 * (r >> 2) + 4 * h2;
                const int addr = ((l31 >> 4) << 9) + ((co + 32 * ((l31 >> 3) & 1)) << 3)
                               + (l31 & 7);
                vt_[addr] = f2bf(acc[r]);
            }
        }
    }
}

// ---------------- Flash attention (round-6 structure + swizzle + asm exp) ---
// Flat grid 256, XCD-batch-affinity bijective decode. block 512 = 8 waves =
// 4 j-quarters x 2 q-subwaves; per 32-key step each jq pair stages its 18KB
// tile via 18 global_load_lds (compile-time-resolved split), lane-linear
// conflict-free ds_read_b128, swapped-operand MFMA flash with exp2-domain
// lane-local softmax (bare v_exp_f32), 4-way phased j-combine.
__global__ __launch_bounds__(512) void attn_kernel(
    const unsigned short* __restrict__ qb, const unsigned short* __restrict__ kfrag,
    const unsigned short* __restrict__ vfrag,
    const float* __restrict__ x, const float* __restrict__ gamma,
    float* __restrict__ out)
{
    const int tid  = threadIdx.x;
    const int wave = tid >> 6;
    const int lane = tid & 63;
    const int l31  = lane & 31;
    const int h2   = lane >> 5;
    const int jq   = wave >> 1;
    const int qs   = wave & 1;

    // XCD-affinity decode (bijective): bid = slot*8 + xcd
    const int bid  = blockIdx.x;
    const int xcd  = bid & 7;
    const int slot = bid >> 3;
    const int b    = xcd >> 1;               // 2 XCDs per batch
    const int ib   = slot * 2 + (xcd & 1);   // i-tile 0..63
    const int iq   = ib * 64 + 32 * qs;

    __shared__ char lds[NSTG];
    __shared__ float m_sh[8][32];
    __shared__ float l_sh[8][32];

    const unsigned short* vtb = vfrag + (size_t)b * 128 * 8192;
    const unsigned short* ktb = kfrag + (size_t)b * 128 * 1024;

    char* reg0 = lds + (jq * 2) * TILEB;
    char* reg1 = reg0 + TILEB;

    // Q B-fragments (one-time scattered load)
    short8 qf0 = *reinterpret_cast<const short8*>(
        qb + ((size_t)b * N_ + iq + l31) * 32 + 8 * h2);
    short8 qf1 = *reinterpret_cast<const short8*>(
        qb + ((size_t)b * N_ + iq + l31) * 32 + 8 * h2 + 16);

    f32x16 acc[8];
    #pragma unroll
    for (int g = 0; g < 8; ++g)
        #pragma unroll
        for (int r = 0; r < 16; ++r) acc[g][r] = 0.f;

    float m_run = 0.f;   // defer-max init (exp2 domain)
    float l_run = 0.f;
    const f32x16 z16 = {};

    // ---- prologue: stage tile 0 ----
    {
        const char* vs = (const char*)(vtb + (size_t)(jq * 32) * 8192);
        const char* ks = (const char*)(ktb + (size_t)(jq * 32) * 1024);
        #pragma unroll
        for (int s2 = 0; s2 < 9; ++s2) {
            const int off = qs * 9216 + s2 * 1024;
            const char* g = (off < 16384) ? (vs + off) : (ks + (off - 16384));
            gload16(g + lane * 16, reg0 + off);
        }
    }
    __syncthreads();

    #pragma unroll 1
    for (int t = 0; t < 32; ++t) {
        char* cur = (t & 1) ? reg1 : reg0;
        char* nxt = (t & 1) ? reg0 : reg1;

        // stage next tile (issue before compute; lands by end-of-step barrier)
        if (t < 31) {
            const int jtg = jq * 32 + t + 1;
            const char* vs = (const char*)(vtb + (size_t)jtg * 8192);
            const char* ks = (const char*)(ktb + (size_t)jtg * 1024);
            #pragma unroll
            for (int s2 = 0; s2 < 9; ++s2) {
                const int off = qs * 9216 + s2 * 1024;
                const char* g = (off < 16384) ? (vs + off) : (ks + (off - 16384));
                gload16(g + lane * 16, nxt + off);
            }
        }

        // ---- QK^T (swapped): S^T[j][i], scores already in log2 units ----
        const char* kt_ = cur + 16384;
        short8 ka0 = *reinterpret_cast<const short8*>(kt_ + lane * 16);
        short8 ka1 = *reinterpret_cast<const short8*>(kt_ + 1024 + lane * 16);
        f32x16 s = __builtin_amdgcn_mfma_f32_32x32x16_bf16(ka0, qf0, z16, 0, 0, 0);
        s = __builtin_amdgcn_mfma_f32_32x32x16_bf16(ka1, qf1, s, 0, 0, 0);

        // ---- online softmax (exp2 domain), lane-local (i = l31) ----
        float a0 = fmaxf(s[0], s[8]),  a1 = fmaxf(s[1], s[9]);
        float a2 = fmaxf(s[2], s[10]), a3 = fmaxf(s[3], s[11]);
        float a4 = fmaxf(s[4], s[12]), a5 = fmaxf(s[5], s[13]);
        float a6 = fmaxf(s[6], s[14]), a7 = fmaxf(s[7], s[15]);
        a0 = fmaxf(a0, a4); a1 = fmaxf(a1, a5); a2 = fmaxf(a2, a6); a3 = fmaxf(a3, a7);
        float smax = fmaxf(fmaxf(a0, a1), fmaxf(a2, a3));

        if (__any(smax > m_run + 8.0f)) {    // defer-max: rare slow path
            float sm2 = fmaxf(smax, __shfl_xor(smax, 32));
            float mnew = fmaxf(m_run, sm2);
            float corr = exp2a(m_run - mnew);
            m_run = mnew;
            l_run *= corr;
            #pragma unroll
            for (int g = 0; g < 8; ++g)
                #pragma unroll
                for (int r = 0; r < 16; ++r) acc[g][r] *= corr;
        }

        float p[16];
        float lsum = 0.f;
        #pragma unroll
        for (int r = 0; r < 16; ++r) { p[r] = exp2a(s[r] - m_run); lsum += p[r]; }
        l_run += lsum;

        unsigned int X0 = cvtpk(p[0],  p[1]),  X1 = cvtpk(p[2],  p[3]);
        unsigned int Y0 = cvtpk(p[4],  p[5]),  Y1 = cvtpk(p[6],  p[7]);
        unsigned int W0 = cvtpk(p[8],  p[9]),  W1 = cvtpk(p[10], p[11]);
        unsigned int V0 = cvtpk(p[12], p[13]), V1 = cvtpk(p[14], p[15]);
        pl32swap(X0, Y0); pl32swap(X1, Y1);
        pl32swap(W0, V0); pl32swap(W1, V1);
        short8 pb0 = __builtin_bit_cast(short8, u32x4{X0, X1, Y0, Y1});
        short8 pb1 = __builtin_bit_cast(short8, u32x4{W0, W1, V0, V1});

        // ---- PV: lane-linear V fragment reads from LDS ----
        __builtin_amdgcn_s_setprio(1);
        #pragma unroll
        for (int g = 0; g < 8; ++g) {
            short8 va0 = *reinterpret_cast<const short8*>(cur + g * 2048 + lane * 16);
            short8 va1 = *reinterpret_cast<const short8*>(cur + g * 2048 + 1024 + lane * 16);
            acc[g] = __builtin_amdgcn_mfma_f32_32x32x16_bf16(va0, pb0, acc[g], 0, 0, 0);
            acc[g] = __builtin_amdgcn_mfma_f32_32x32x16_bf16(va1, pb1, acc[g], 0, 0, 0);
        }
        __builtin_amdgcn_s_setprio(0);

        __syncthreads();   // drains vmcnt (next tile landed) + guards buffers
    }

    // ---- 4-way j-combine ----
    float l_tot = l_run + __shfl_xor(l_run, 32);
    if (lane < 32) { m_sh[wave][lane] = m_run; l_sh[wave][lane] = l_tot; }
    __syncthreads();

    float M = -1e30f, L = 0.f;
    #pragma unroll
    for (int w2 = 0; w2 < 4; ++w2) M = fmaxf(M, m_sh[w2 * 2 + qs][l31]);
    #pragma unroll
    for (int w2 = 0; w2 < 4; ++w2)
        L += exp2a(m_sh[w2 * 2 + qs][l31] - M) * l_sh[w2 * 2 + qs][l31];
    const float wgt = exp2a(m_run - M);
    #pragma unroll
    for (int g = 0; g < 8; ++g)
        #pragma unroll
        for (int r = 0; r < 16; ++r) acc[g][r] *= wgt;

    // phase A: jq2,jq3 dump -> D[(jq-2)*2+qs]; jq0,jq1 add
    if (jq >= 2) {
        f32x4* Dr = (f32x4*)(lds + ((jq - 2) * 2 + qs) * 32768);
        #pragma unroll
        for (int g = 0; g < 8; ++g)
            #pragma unroll
            for (int r4 = 0; r4 < 4; ++r4) {
                f32x4 tv;
                #pragma unroll
                for (int e = 0; e < 4; ++e) tv[e] = acc[g][4 * r4 + e];
                Dr[(g * 4 + r4) * 64 + lane] = tv;
            }
    }
    __syncthreads();
    if (jq < 2) {
        const f32x4* Dr = (const f32x4*)(lds + (jq * 2 + qs) * 32768);
        #pragma unroll
        for (int g = 0; g < 8; ++g)
            #pragma unroll
            for (int r4 = 0; r4 < 4; ++r4) {
                f32x4 tv = Dr[(g * 4 + r4) * 64 + lane];
                #pragma unroll
                for (int e = 0; e < 4; ++e) acc[g][4 * r4 + e] += tv[e];
            }
    }
    __syncthreads();
    // phase B: jq1 dump -> D[2+qs]; jq0 add; jq0 dump final -> D[qs]
    if (jq == 1) {
        f32x4* Dr = (f32x4*)(lds + (2 + qs) * 32768);
        #pragma unroll
        for (int g = 0; g < 8; ++g)
            #pragma unroll
            for (int r4 = 0; r4 < 4; ++r4) {
                f32x4 tv;
                #pragma unroll
                for (int e = 0; e < 4; ++e) tv[e] = acc[g][4 * r4 + e];
                Dr[(g * 4 + r4) * 64 + lane] = tv;
            }
    }
    __syncthreads();
    if (jq == 0) {
        const f32x4* Dr = (const f32x4*)(lds + (2 + qs) * 32768);
        f32x4* Dw = (f32x4*)(lds + qs * 32768);
        #pragma unroll
        for (int g = 0; g < 8; ++g)
            #pragma unroll
            for (int r4 = 0; r4 < 4; ++r4) {
                f32x4 tv = Dr[(g * 4 + r4) * 64 + lane];
                #pragma unroll
                for (int e = 0; e < 4; ++e) tv[e] += acc[g][4 * r4 + e];
                Dw[(g * 4 + r4) * 64 + lane] = tv;
            }
    }
    __syncthreads();

    // ---- store: wave w -> q-subwave (w&1)==qs, g-pair (w>>1)==jq ----
    const float gma  = gamma[0];
    const float invL = 1.f / L;
    const f32x4* Ds = (const f32x4*)(lds + qs * 32768);
    const int i = iq + l31;
    #pragma unroll
    for (int gi = 0; gi < 2; ++gi) {
        const int g = jq * 2 + gi;
        #pragma unroll
        for (int r4 = 0; r4 < 4; ++r4) {
            f32x4 v = Ds[(g * 4 + r4) * 64 + lane];
            #pragma unroll
            for (int e = 0; e < 4; ++e) {
                const int c = 32 * g + e + 8 * r4 + 4 * h2;
                const size_t off = ((size_t)b * C_ + c) * N_ + i;
                out[off] = gma * v[e] * invL + x[off];
            }
        }
    }
}

extern "C" void kernel_launch(void* const* d_in, const int* in_sizes, int n_in,
                              void* d_out, int out_size, void* d_ws, size_t ws_size,
                              hipStream_t stream) {
    const float* x     = (const float*)d_in[0];
    const float* Wq    = (const float*)d_in[1];
    const float* bq    = (const float*)d_in[2];
    const float* Wk    = (const float*)d_in[3];
    const float* bk    = (const float*)d_in[4];
    const float* Wv    = (const float*)d_in[5];
    const float* bv    = (const float*)d_in[6];
    const float* gamma = (const float*)d_in[7];
    float* out = (float*)d_out;

    unsigned short* ws = (unsigned short*)d_ws;
    unsigned short* qb    = ws;                                 // B*N*32 bf16
    unsigned short* kfrag = qb + (size_t)B_ * N_ * INTER_;      // B*128*1024 bf16
    unsigned short* vfrag = kfrag + (size_t)B_ * 128 * 1024;    // B*128*8192 bf16
    unsigned short* wb    = vfrag + (size_t)B_ * 128 * 8192;    // 320*256 bf16

    prep_kernel<<<dim3(320), 256, 0, stream>>>(Wq, Wk, Wv, wb);
    qkv_kernel<<<dim3(B_ * (N_ / 64)), 256, 0, stream>>>(
        x, wb, bq, bk, bv, qb, kfrag, vfrag);
    attn_kernel<<<dim3(256), 512, 0, stream>>>(
        qb, kfrag, vfrag, x, gamma, out);
}